// Round 7
// baseline (1553.162 us; speedup 1.0000x reference)
//
#include <hip/hip_runtime.h>
#include <hip/hip_bf16.h>
#include <math.h>

#define BB 16
#define NT 197
#define EE 768
#define HH 12
#define E2 1536
#define MLPD 3072
#define NCLS 1000
#define ND 6
#define EPSF 1e-5f
#define SCALEF 0.125f
#define LAMINIT 0.8f
#define TOKC 3152

using v8bf  = __attribute__((ext_vector_type(8))) __bf16;
using f32x4 = __attribute__((ext_vector_type(4))) float;
typedef __hip_bfloat16 bf16;

#define AS1 __attribute__((address_space(1)))
#define AS3 __attribute__((address_space(3)))

__device__ __forceinline__ void gld16(const void* g, void* l) {
    __builtin_amdgcn_global_load_lds((const AS1 void*)g, (AS3 void*)l, 16, 0, 0);
}

__device__ __forceinline__ float gelu_f(float x) {
    const float u = x + 0.044715f * x * x * x;
    const float e = __expf(fminf(1.5957691216f * u, 80.f));
    return x * e / (e + 1.f);
}

// ================= bf16 MFMA GEMM: C[M][N] = A[M][K] @ Wt[N][K]^T =================
// 128x128 tile, BK=64, 256 threads (4 waves 2x2), wave 64x64 (4x4 frags).
// Kept for small-N shapes (conv mode 4, Wo/MLP2 mode 0 with split-K).
__global__ __launch_bounds__(256) void gemm_bf16(
    const bf16* __restrict__ A, const bf16* __restrict__ Wt,
    const float* __restrict__ bias, float* __restrict__ C0,
    float* __restrict__ C1, float* __restrict__ C2,
    const float* __restrict__ pos, int M, int K, int ldA, int ldB, int Nc, int mode)
{
    __shared__ __align__(16) unsigned char smem[32768];
    const int t = threadIdx.x;
    const int wave = t >> 6, lane = t & 63;
    const int wr = wave >> 1, wc = wave & 1;
    const int lr = lane & 15, lk = lane >> 4;

    const int bid0 = blockIdx.y * gridDim.x + blockIdx.x;
    const int nwg = gridDim.x * gridDim.y;
    const int qv = nwg >> 3, rv = nwg & 7;
    const int xcd = bid0 & 7, ii = bid0 >> 3;
    const int wgid = (xcd < rv ? xcd * (qv + 1) : rv * (qv + 1) + (xcd - rv) * qv) + ii;
    const int rowBase = (wgid / gridDim.x) * 128;
    const int colBase = (wgid % gridDim.x) * 128;
    const size_t zoff = (size_t)blockIdx.z * K * 2;

    f32x4 acc[4][4];
#pragma unroll
    for (int i = 0; i < 4; ++i)
#pragma unroll
        for (int j = 0; j < 4; ++j) acc[i][j] = (f32x4){0.f,0.f,0.f,0.f};

    const size_t ldA2 = (size_t)ldA * 2, ldB2 = (size_t)ldB * 2;
    const int srow = t >> 3;
    const int schunk = (t & 7) ^ ((t >> 3) & 7);
    const char* Abase = (const char*)A + zoff + schunk * 16;
    const char* Bbase = (const char*)Wt + zoff + schunk * 16;
    unsigned char* lA = smem + t * 16;
    unsigned char* lB = smem + 16384 + t * 16;
    const v8bf* Sa = (const v8bf*)smem;
    const v8bf* Sb = (const v8bf*)(smem + 16384);

    int rA[4], rB[4];
#pragma unroll
    for (int c = 0; c < 4; ++c) {
        rA[c] = min(rowBase + c * 32 + srow, M - 1);
        rB[c] = colBase + c * 32 + srow;
    }

    for (int k0 = 0; k0 < K; k0 += 64) {
        const size_t kb = (size_t)k0 * 2;
#pragma unroll
        for (int c = 0; c < 4; ++c) {
            gld16(Abase + (size_t)rA[c] * ldA2 + kb, lA + c * 4096);
            gld16(Bbase + (size_t)rB[c] * ldB2 + kb, lB + c * 4096);
        }
        __syncthreads();
#pragma unroll
        for (int s = 0; s < 2; ++s) {
            const int xr_ = (s * 4 + lk) ^ (lr & 7);
            v8bf af[4], bfr[4];
#pragma unroll
            for (int i = 0; i < 4; ++i) af[i] = Sa[(wr * 64 + i * 16 + lr) * 8 + xr_];
#pragma unroll
            for (int j = 0; j < 4; ++j) bfr[j] = Sb[(wc * 64 + j * 16 + lr) * 8 + xr_];
#pragma unroll
            for (int i = 0; i < 4; ++i)
#pragma unroll
                for (int j = 0; j < 4; ++j)
                    acc[i][j] = __builtin_amdgcn_mfma_f32_16x16x32_bf16(af[i], bfr[j], acc[i][j], 0, 0, 0);
        }
        __syncthreads();
    }

    // ---------------- epilogues (smem reused) ----------------
    if (mode == 0) {
        float* Cs = (float*)smem;                 // [64][128]
        float* C0z = C0 + (size_t)blockIdx.z * M * Nc;
#pragma unroll
        for (int half = 0; half < 2; ++half) {
            __syncthreads();
            if (wr == half) {
#pragma unroll
                for (int i = 0; i < 4; ++i)
#pragma unroll
                    for (int j = 0; j < 4; ++j)
#pragma unroll
                        for (int rr = 0; rr < 4; ++rr)
                            Cs[(i*16 + lk*4 + rr)*128 + wc*64 + j*16 + lr] = acc[i][j][rr];
            }
            __syncthreads();
#pragma unroll
            for (int k = 0; k < 8; ++k) {
                const int idx = k*256 + t;
                const int row = idx >> 5, c4 = idx & 31;
                const int r = rowBase + half*64 + row;
                if (r < M)
                    *(float4*)&C0z[(size_t)r*Nc + colBase + c4*4] = *(float4*)&Cs[row*128 + c4*4];
            }
        }
    } else if (mode == 1) {
        const int which = colBase / E2;
        if (which == 2) {
#pragma unroll
            for (int i = 0; i < 4; ++i)
#pragma unroll
                for (int j = 0; j < 4; ++j)
#pragma unroll
                    for (int rr = 0; rr < 4; ++rr) {
                        const int r = rowBase + wr * 64 + i * 16 + lk * 4 + rr;
                        const int c = colBase + wc * 64 + j * 16 + lr;
                        if (r >= M) continue;
                        const int b_ = r / NT, n_ = r % NT;
                        const int cc = c % E2;
                        const int h_ = cc >> 7, d_ = cc & 127;
                        const size_t bh = (size_t)(b_ * HH + h_);
                        ((bf16*)C2)[((bh * 7 + (n_ >> 5)) * 8 + (d_ >> 4)) * 512 +
                                    (size_t)(((d_ & 15) + (((n_ >> 3) & 3) << 4)) * 8 + (n_ & 7))] =
                            __float2bfloat16(acc[i][j][rr]);
                    }
        } else {
            const int hFix = (colBase % E2) >> 7;
            bf16* dstBase = (bf16*)(which == 0 ? C0 : C1);
            bf16* Cs = (bf16*)smem;               // [128][128]
            __syncthreads();
#pragma unroll
            for (int i = 0; i < 4; ++i)
#pragma unroll
                for (int j = 0; j < 4; ++j)
#pragma unroll
                    for (int rr = 0; rr < 4; ++rr)
                        Cs[(wr*64 + i*16 + lk*4 + rr)*128 + wc*64 + j*16 + lr] =
                            __float2bfloat16(acc[i][j][rr]);
            __syncthreads();
#pragma unroll
            for (int k = 0; k < 8; ++k) {
                const int idx = k*256 + t;
                const int row = idx >> 4, c8 = idx & 15;
                const int r = rowBase + row;
                if (r < M) {
                    const int b_ = r / NT, n_ = r - b_ * NT;
                    const size_t bh = (size_t)(b_ * HH + hFix);
                    *(uint4*)(dstBase + (bh * 208 + n_) * 128 + c8 * 8) =
                        *(uint4*)&Cs[row*128 + c8*8];
                }
            }
        }
    } else if (mode == 3) {
        bf16* Cs = (bf16*)smem;                   // [128][128]
        __syncthreads();
#pragma unroll
        for (int i = 0; i < 4; ++i)
#pragma unroll
            for (int j = 0; j < 4; ++j)
#pragma unroll
                for (int rr = 0; rr < 4; ++rr) {
                    const int c = colBase + wc*64 + j*16 + lr;
                    float val = acc[i][j][rr] + bias[c];
                    Cs[(wr*64 + i*16 + lk*4 + rr)*128 + wc*64 + j*16 + lr] =
                        __float2bfloat16(gelu_f(val));
                }
        __syncthreads();
        bf16* C0b = (bf16*)C0;
#pragma unroll
        for (int k = 0; k < 8; ++k) {
            const int idx = k*256 + t;
            const int row = idx >> 4, c8 = idx & 15;
            const int r = rowBase + row;
            if (r < M)
                *(uint4*)(C0b + (size_t)r*Nc + colBase + c8*8) = *(uint4*)&Cs[row*128 + c8*8];
        }
    } else { // mode 4: patch scatter
#pragma unroll
        for (int i = 0; i < 4; ++i)
#pragma unroll
            for (int j = 0; j < 4; ++j)
#pragma unroll
                for (int rr = 0; rr < 4; ++rr) {
                    const int r = rowBase + wr * 64 + i * 16 + lk * 4 + rr;
                    const int c = colBase + wc * 64 + j * 16 + lr;
                    if (r >= M) continue;
                    const int b_ = r / 196, p_ = r % 196;
                    C0[((size_t)(b_ * NT) + 1 + p_) * EE + c] =
                        acc[i][j][rr] + bias[c] + pos[(size_t)(1 + p_) * EE + c];
                }
    }
}

// ================= 256xNB-tile deep-pipelined bf16 GEMM (8 waves) ==============
// BM=256, BN=NF*64 (NF=4: 256 wide, NF=3: 192 wide for MLP1 grid coverage).
// 512 threads (2M x 4N waves), wave computes 128 x NF*16 frags.
// LDS double-buffered (A 32KB + B NF*8KB per buf), chunk-XOR swizzle both-sides.
// Counted vmcnt (never 0 in steady state), raw s_barrier, setprio around MFMA.
// 2-phase schedule (round-2 best; 4-phase variant measured WORSE — barrier cost).
// modes: 1 = QKV scatter (NF=4 only), 3 = bias+gelu bf16.
// V-epilogue: LDS-staged (chunk-XOR swizzled) + 8-token-packed 16B stores;
// the old per-element 2B register scatter was ~64 transactions per wave-store.
template<int NF>
__global__ __launch_bounds__(512, 2) void gemm256t(
    const bf16* __restrict__ A, const bf16* __restrict__ Wt,
    const float* __restrict__ bias, float* __restrict__ C0,
    float* __restrict__ C1, float* __restrict__ C2,
    int M, int K, int Nc, int mode)
{
    constexpr int NB = NF * 64;
    constexpr int BUFSZ = 32768 + NF * 8192;
    __shared__ __align__(16) unsigned char smem[2 * BUFSZ];
    const int t = threadIdx.x;
    const int wave = t >> 6, lane = t & 63;
    const int wm = wave >> 2, wn = wave & 3;
    const int lr = lane & 15, lk = lane >> 4;

    const int bid0 = blockIdx.y * gridDim.x + blockIdx.x;
    const int nwg = gridDim.x * gridDim.y;
    const int qv = nwg >> 3, rv = nwg & 7;
    const int xcd = bid0 & 7, ii = bid0 >> 3;
    const int wgid = (xcd < rv ? xcd * (qv + 1) : rv * (qv + 1) + (xcd - rv) * qv) + ii;
    const int rowBase = (wgid / gridDim.x) * 256;
    const int colBase = (wgid % gridDim.x) * NB;

    f32x4 acc[8][NF];
#pragma unroll
    for (int i = 0; i < 8; ++i)
#pragma unroll
        for (int j = 0; j < NF; ++j) acc[i][j] = (f32x4){0.f,0.f,0.f,0.f};

    const size_t ldK2 = (size_t)K * 2;
    const int srow = t >> 3;                       // 0..63
    const int schunk = (t & 7) ^ (srow & 7);       // pre-swizzled global chunk
    const char* Abase = (const char*)A + schunk * 16;
    const char* Bbase = (const char*)Wt + schunk * 16;

    int rA[4], rB[NF];
#pragma unroll
    for (int p = 0; p < 4; ++p) rA[p] = min(rowBase + p * 64 + srow, M - 1);
#pragma unroll
    for (int p = 0; p < NF; ++p) rB[p] = colBase + p * 64 + srow;

    // ---- prologue: stage tile0 -> buf0, tile1 -> buf1 ----
    {
        unsigned char* l0 = smem + t * 16;
#pragma unroll
        for (int p = 0; p < 4; ++p) gld16(Abase + (size_t)rA[p] * ldK2, l0 + p * 8192);
#pragma unroll
        for (int p = 0; p < NF; ++p) gld16(Bbase + (size_t)rB[p] * ldK2, l0 + 32768 + p * 8192);
#pragma unroll
        for (int p = 0; p < 4; ++p) gld16(Abase + (size_t)rA[p] * ldK2 + 128, l0 + BUFSZ + p * 8192);
#pragma unroll
        for (int p = 0; p < NF; ++p) gld16(Bbase + (size_t)rB[p] * ldK2 + 128, l0 + BUFSZ + 32768 + p * 8192);
        if constexpr (NF == 4) asm volatile("s_waitcnt vmcnt(8)" ::: "memory");
        else                   asm volatile("s_waitcnt vmcnt(7)" ::: "memory");
        asm volatile("s_barrier" ::: "memory");
    }

    const int NTt = K >> 6;
    for (int kt = 0; kt < NTt; ++kt) {
        const int buf = kt & 1;
        const v8bf* Sa = (const v8bf*)(smem + buf * BUFSZ);
        const v8bf* Sb = (const v8bf*)(smem + buf * BUFSZ + 32768);

        // ---- phase A: read B(all) + A(half0), MFMA quadrant mh=0 ----
        v8bf bfr[2][NF], af[2][4];
#pragma unroll
        for (int s = 0; s < 2; ++s) {
            const int x0 = s * 4 + lk;
#pragma unroll
            for (int j = 0; j < NF; ++j) {
                const int row = wn * (NF * 16) + j * 16 + lr;
                bfr[s][j] = Sb[row * 8 + (x0 ^ (lr & 7))];
            }
#pragma unroll
            for (int i = 0; i < 4; ++i) {
                const int row = wm * 128 + i * 16 + lr;
                af[s][i] = Sa[row * 8 + (x0 ^ (lr & 7))];
            }
        }
        __builtin_amdgcn_s_setprio(1);
#pragma unroll
        for (int s = 0; s < 2; ++s)
#pragma unroll
            for (int i = 0; i < 4; ++i)
#pragma unroll
                for (int j = 0; j < NF; ++j)
                    acc[i][j] = __builtin_amdgcn_mfma_f32_16x16x32_bf16(af[s][i], bfr[s][j], acc[i][j], 0, 0, 0);
        __builtin_amdgcn_s_setprio(0);

        // ---- phase B: read A(half1), release buf, prefetch kt+2, MFMA mh=1 ----
        v8bf af2[2][4];
#pragma unroll
        for (int s = 0; s < 2; ++s)
#pragma unroll
            for (int i = 0; i < 4; ++i) {
                const int row = wm * 128 + 64 + i * 16 + lr;
                af2[s][i] = Sa[row * 8 + ((s * 4 + lk) ^ (lr & 7))];
            }
        asm volatile("s_waitcnt lgkmcnt(0)" ::: "memory");   // my reads of buf done
        asm volatile("s_barrier" ::: "memory");              // all waves done reading buf
        if (kt + 2 < NTt) {
            const size_t kb = (size_t)(kt + 2) * 128;
            unsigned char* ld = smem + buf * BUFSZ + t * 16;
#pragma unroll
            for (int p = 0; p < 4; ++p) gld16(Abase + (size_t)rA[p] * ldK2 + kb, ld + p * 8192);
#pragma unroll
            for (int p = 0; p < NF; ++p) gld16(Bbase + (size_t)rB[p] * ldK2 + kb, ld + 32768 + p * 8192);
            if constexpr (NF == 4) asm volatile("s_waitcnt vmcnt(8)" ::: "memory");
            else                   asm volatile("s_waitcnt vmcnt(7)" ::: "memory");
        } else {
            asm volatile("s_waitcnt vmcnt(0)" ::: "memory"); // drain tail
        }
        asm volatile("s_barrier" ::: "memory");              // everyone's kt+1 landed
        __builtin_amdgcn_s_setprio(1);
#pragma unroll
        for (int s = 0; s < 2; ++s)
#pragma unroll
            for (int i = 0; i < 4; ++i)
#pragma unroll
                for (int j = 0; j < NF; ++j)
                    acc[4 + i][j] = __builtin_amdgcn_mfma_f32_16x16x32_bf16(af2[s][i], bfr[s][j], acc[4 + i][j], 0, 0, 0);
        __builtin_amdgcn_s_setprio(0);
    }

    // ---------------- epilogues (smem reused) ----------------
    if constexpr (NF == 4) {
        if (mode == 1) {
            const int which = colBase / E2;
            if (which == 2) {
                // V: LDS-staged (chunk-XOR swizzle) + packed 8-token 16B stores.
                bf16* Cs = (bf16*)smem;           // [256][256], 128 KB exactly
                __syncthreads();
#pragma unroll
                for (int i = 0; i < 8; ++i)
#pragma unroll
                    for (int j = 0; j < 4; ++j)
#pragma unroll
                        for (int rr = 0; rr < 4; ++rr) {
                            const int rl = wm*128 + i*16 + lk*4 + rr;
                            const int cl = wn*64 + j*16 + lr;
                            const int phys = ((cl >> 3) ^ (rl & 31)) & 31;
                            Cs[rl*256 + phys*8 + (cl & 7)] =
                                __float2bfloat16(acc[i][j][rr]);
                        }
                __syncthreads();
                const int rows = min(256, M - rowBase);
                bf16* Vfb = (bf16*)C2;
                // packed pass: octets of 8 tokens fully inside this block
                for (int s = 0; s < 256; s += 2) {
                    const int rl0 = s + (t >> 8);
                    const int r0 = rowBase + rl0;
                    const int b_ = r0 / NT;
                    const int n0 = r0 - b_ * NT;
                    if ((n0 & 7) == 0 && n0 < 192 && rl0 + 7 < rows) {
                        const int d = t & 255;
                        const int cc = colBase - 2*E2 + d;
                        const int h_ = cc >> 7, d_ = cc & 127;
                        const size_t bh = (size_t)(b_ * HH + h_);
                        bf16 pk[8];
#pragma unroll
                        for (int j = 0; j < 8; ++j) {
                            const int rj = rl0 + j;
                            pk[j] = Cs[rj*256 + ((((d>>3) ^ (rj & 31)) & 31)<<3) + (d & 7)];
                        }
                        *(uint4*)&Vfb[((bh*7 + (n0>>5))*8 + (d_>>4))*512 +
                                      (size_t)(((d_ & 15) + (((n0>>3)&3)<<4))*8)] =
                            *(uint4*)pk;
                    }
                }
                // scalar pass: rows in boundary-straddling octets + n>=192 tail
                for (int rl = 0; rl < rows; ++rl) {
                    const int r = rowBase + rl;
                    const int b_ = r / NT;
                    const int n_ = r - b_ * NT;
                    const int st = rl - (n_ & 7);
                    const bool covered = (n_ < 192) && (st >= 0) && (st + 7 < rows);
                    if (covered) continue;
                    for (int d = t; d < 256; d += 512) {
                        const int cc = colBase - 2*E2 + d;
                        const int h_ = cc >> 7, d_ = cc & 127;
                        const size_t bh = (size_t)(b_ * HH + h_);
                        Vfb[((bh*7 + (n_>>5))*8 + (d_>>4))*512 +
                            (size_t)(((d_ & 15) + (((n_>>3)&3)<<4))*8 + (n_ & 7))] =
                            Cs[rl*256 + ((((d>>3) ^ (rl & 31)) & 31)<<3) + (d & 7)];
                    }
                }
            } else {
                bf16* dstBase = (bf16*)(which == 0 ? C0 : C1);
                const int h0 = (colBase % E2) >> 7;   // tile spans heads h0, h0+1
                bf16* Cs = (bf16*)smem;               // [256][256]
                __syncthreads();
#pragma unroll
                for (int i = 0; i < 8; ++i)
#pragma unroll
                    for (int j = 0; j < 4; ++j)
#pragma unroll
                        for (int rr = 0; rr < 4; ++rr)
                            Cs[(wm*128 + i*16 + lk*4 + rr)*256 + wn*64 + j*16 + lr] =
                                __float2bfloat16(acc[i][j][rr]);
                __syncthreads();
#pragma unroll
                for (int k = 0; k < 16; ++k) {
                    const int idx = k * 512 + t;
                    const int row = idx >> 5, c8 = idx & 31;
                    const int r = rowBase + row;
                    if (r < M) {
                        const int b_ = r / NT, n_ = r - b_ * NT;
                        const size_t bh = (size_t)(b_ * HH + h0 + (c8 >> 4));
                        *(uint4*)(dstBase + (bh * 208 + n_) * 128 + (size_t)(c8 & 15) * 8) =
                            *(uint4*)&Cs[row * 256 + c8 * 8];
                    }
                }
            }
            return;
        }
    }
    { // mode 3: bias + gelu -> bf16 row-major
        bf16* Cs = (bf16*)smem;                   // [256][NB]
        __syncthreads();
#pragma unroll
        for (int i = 0; i < 8; ++i)
#pragma unroll
            for (int j = 0; j < NF; ++j) {
                const int c = colBase + wn * (NF * 16) + j * 16 + lr;
                const float bv = bias[c];
#pragma unroll
                for (int rr = 0; rr < 4; ++rr)
                    Cs[(wm*128 + i*16 + lk*4 + rr)*NB + wn*(NF*16) + j*16 + lr] =
                        __float2bfloat16(gelu_f(acc[i][j][rr] + bv));
            }
        __syncthreads();
        bf16* C0b = (bf16*)C0;
        constexpr int CW = NB / 8;                // uint4 chunks per row
        constexpr int ITER = 256 * CW / 512;
#pragma unroll
        for (int k = 0; k < ITER; ++k) {
            const int idx = k * 512 + t;
            const int row = idx / CW, c8 = idx - row * CW;
            const int r = rowBase + row;
            if (r < M)
                *(uint4*)(C0b + (size_t)r * Nc + colBase + c8 * 8) =
                    *(uint4*)&Cs[row * NB + c8 * 8];
        }
    }
}

// ================= MFMA differential attention: 1 wave per (bh, 16-q-rows) ====
__global__ __launch_bounds__(64) void attn_mfma(
    const bf16* __restrict__ Qrm, const bf16* __restrict__ Krm,
    const bf16* __restrict__ Vf, const float* __restrict__ lamp,
    float* __restrict__ aout, float* __restrict__ o, float* __restrict__ stats)
{
    const int lane = threadIdx.x;
    const int fid = blockIdx.x;
    const int xcd = fid & 7, rest = fid >> 3;
    const int qt = rest % 13, g = rest / 13;
    const int bh = g * 8 + xcd;
    const int hh = bh % HH;
    const int lr = lane & 15, lk = lane >> 4;

    __shared__ __align__(16) bf16 P[16][232];

    {
        const int r = lane & 15, c0 = 192 + (lane >> 4) * 10;
#pragma unroll
        for (int j = 0; j < 10; ++j) P[r][c0 + j] = __float2bfloat16(0.f);
    }

    v8bf qa[4];
    const bf16* Qb = Qrm + ((size_t)bh * 208 + qt * 16) * 128;
#pragma unroll
    for (int kk = 0; kk < 4; ++kk)
        qa[kk] = *(const v8bf*)(Qb + lr * 128 + kk * 32 + lk * 8);

    const bf16* Kb = Krm + (size_t)bh * 208 * 128;
    const f32x4 zf = {0.f, 0.f, 0.f, 0.f};
    f32x4 s1[13], s2[13];
#pragma unroll
    for (int t = 0; t < 13; ++t) {
        const bf16* Kt = Kb + (t * 16 + lr) * 128 + lk * 8;
        const v8bf k0 = *(const v8bf*)(Kt);
        const v8bf k1 = *(const v8bf*)(Kt + 32);
        const v8bf k2 = *(const v8bf*)(Kt + 64);
        const v8bf k3 = *(const v8bf*)(Kt + 96);
        s1[t] = __builtin_amdgcn_mfma_f32_16x16x32_bf16(qa[1], k1,
                __builtin_amdgcn_mfma_f32_16x16x32_bf16(qa[0], k0, zf, 0, 0, 0), 0, 0, 0);
        s2[t] = __builtin_amdgcn_mfma_f32_16x16x32_bf16(qa[3], k3,
                __builtin_amdgcn_mfma_f32_16x16x32_bf16(qa[2], k2, zf, 0, 0, 0), 0, 0, 0);
    }

    float m1[4] = {-1e30f,-1e30f,-1e30f,-1e30f}, m2[4] = {-1e30f,-1e30f,-1e30f,-1e30f};
#pragma unroll
    for (int t = 0; t < 13; ++t) {
        const bool kv = (t * 16 + lr) < NT;
#pragma unroll
        for (int rr = 0; rr < 4; ++rr) {
            s1[t][rr] = kv ? s1[t][rr] * SCALEF : -1e30f;
            s2[t][rr] = kv ? s2[t][rr] * SCALEF : -1e30f;
            m1[rr] = fmaxf(m1[rr], s1[t][rr]);
            m2[rr] = fmaxf(m2[rr], s2[t][rr]);
        }
    }
#pragma unroll
    for (int off = 8; off >= 1; off >>= 1)
#pragma unroll
        for (int rr = 0; rr < 4; ++rr) {
            m1[rr] = fmaxf(m1[rr], __shfl_xor(m1[rr], off));
            m2[rr] = fmaxf(m2[rr], __shfl_xor(m2[rr], off));
        }

    float z1[4] = {0,0,0,0}, z2[4] = {0,0,0,0};
#pragma unroll
    for (int t = 0; t < 13; ++t)
#pragma unroll
        for (int rr = 0; rr < 4; ++rr) {
            const float e1 = __expf(s1[t][rr] - m1[rr]);
            const float e2 = __expf(s2[t][rr] - m2[rr]);
            s1[t][rr] = e1; s2[t][rr] = e2;
            z1[rr] += e1; z2[rr] += e2;
        }
#pragma unroll
    for (int off = 8; off >= 1; off >>= 1)
#pragma unroll
        for (int rr = 0; rr < 4; ++rr) {
            z1[rr] += __shfl_xor(z1[rr], off);
            z2[rr] += __shfl_xor(z2[rr], off);
        }
    const float lam = lamp[hh];
    float r1[4], r2[4];
#pragma unroll
    for (int rr = 0; rr < 4; ++rr) { r1[rr] = 1.f / z1[rr]; r2[rr] = lam / z2[rr]; }

    __syncthreads();
#pragma unroll
    for (int t = 0; t < 13; ++t) {
        const int m_ = t * 16 + lr;
#pragma unroll
        for (int rr = 0; rr < 4; ++rr) {
            const float p = s1[t][rr] * r1[rr] - s2[t][rr] * r2[rr];
            const int n_ = lk * 4 + rr;
            P[n_][m_] = __float2bfloat16(p);
            const int n_g = qt * 16 + n_;
            if (m_ < NT && n_g < NT)
                aout[((size_t)bh * NT + n_g) * NT + m_] = p;
        }
    }
    __syncthreads();

    f32x4 oacc[8];
#pragma unroll
    for (int dt = 0; dt < 8; ++dt) oacc[dt] = zf;
    const v8bf* Vp = (const v8bf*)(Vf + (size_t)bh * 7 * 8 * 512);
    const bf16* Pb = &P[0][0];
#pragma unroll
    for (int mk = 0; mk < 7; ++mk) {
        const v8bf pa = *(const v8bf*)(Pb + lr * 232 + mk * 32 + lk * 8);
#pragma unroll
        for (int dt = 0; dt < 8; ++dt)
            oacc[dt] = __builtin_amdgcn_mfma_f32_16x16x32_bf16(
                pa, Vp[(mk * 8 + dt) * 64 + lane], oacc[dt], 0, 0, 0);
    }
#pragma unroll
    for (int dt = 0; dt < 8; ++dt)
#pragma unroll
        for (int rr = 0; rr < 4; ++rr) {
            const int n_g = qt * 16 + lk * 4 + rr;
            if (n_g < NT)
                o[((size_t)bh * NT + n_g) * 128 + dt * 16 + lr] = oacc[dt][rr];
        }

    float s = 0.f, ss = 0.f;
#pragma unroll
    for (int dt = 0; dt < 8; ++dt)
#pragma unroll
        for (int rr = 0; rr < 4; ++rr) {
            const int n_g = qt * 16 + lk * 4 + rr;
            const float vv = (n_g < NT) ? oacc[dt][rr] : 0.f;
            s += vv; ss += vv * vv;
        }
#pragma unroll
    for (int off = 32; off >= 1; off >>= 1) {
        s  += __shfl_xor(s, off);
        ss += __shfl_xor(ss, off);
    }
    if (lane == 0) {
        stats[(bh * 13 + qt) * 2]     = s;
        stats[(bh * 13 + qt) * 2 + 1] = ss;
    }
}

// ================= GN apply: normalize + relayout (b,n,2E) bf16 ================
__global__ __launch_bounds__(256) void gn_apply(
    const float* __restrict__ o, const float* __restrict__ stats,
    const float* __restrict__ g, const float* __restrict__ bb, bf16* __restrict__ o2)
{
    const int bh = blockIdx.y, qq = blockIdx.x;
    const int t = threadIdx.x;
    float S = 0.f, SS = 0.f;
#pragma unroll
    for (int j = 0; j < 13; ++j) {
        S  += stats[(bh * 13 + j) * 2];
        SS += stats[(bh * 13 + j) * 2 + 1];
    }
    const float inv = 1.f / (float)(NT * 128);
    const float mean = S * inv;
    const float var  = SS * inv - mean * mean;
    const float rstd = rsqrtf(var + EPSF);
    const int b_ = bh / HH, h_ = bh % HH;
    const float4* ob = (const float4*)(o + (size_t)bh * NT * 128);
    const float4* g4 = (const float4*)g;
    const float4* b4 = (const float4*)bb;
    for (int idx = t; idx < 50 * 32; idx += 256) {
        const int n_ = qq * 50 + (idx >> 5);
        if (n_ >= NT) continue;
        const int d4 = idx & 31;
        const float4 v4 = ob[n_ * 32 + d4];
        const float4 gg = g4[d4], bv = b4[d4];
        bf16 tmp[4];
        tmp[0] = __float2bfloat16((v4.x - mean) * rstd * gg.x + bv.x);
        tmp[1] = __float2bfloat16((v4.y - mean) * rstd * gg.y + bv.y);
        tmp[2] = __float2bfloat16((v4.z - mean) * rstd * gg.z + bv.z);
        tmp[3] = __float2bfloat16((v4.w - mean) * rstd * gg.w + bv.w);
        *(uint2*)(o2 + ((size_t)(b_ * NT + n_)) * E2 + h_ * 128 + d4 * 4) = *(uint2*)tmp;
    }
}

// ================= LayerNorm rows -> bf16 (layer 0 entry) =================
__global__ __launch_bounds__(256) void ln_rows(
    const float* __restrict__ in, const float* __restrict__ g,
    const float* __restrict__ bb, bf16* __restrict__ out)
{
    const int r = blockIdx.x;
    const int t = threadIdx.x;
    const float* x = in + (size_t)r * EE;
    const float v0 = x[t], v1 = x[t+256], v2 = x[t+512];
    __shared__ float rs[256], rss[256];
    rs[t]  = v0+v1+v2;
    rss[t] = v0*v0+v1*v1+v2*v2;
    __syncthreads();
    for (int st = 128; st > 0; st >>= 1) {
        if (t < st) { rs[t] += rs[t+st]; rss[t] += rss[t+st]; }
        __syncthreads();
    }
    const float mean = rs[0] * (1.f/768.f);
    const float var  = rss[0] * (1.f/768.f) - mean*mean;
    const float rstd = rsqrtf(var + EPSF);
    bf16* o = out + (size_t)r * EE;
    o[t]     = __float2bfloat16((v0-mean)*rstd*g[t]     + bb[t]);
    o[t+256] = __float2bfloat16((v1-mean)*rstd*g[t+256] + bb[t+256]);
    o[t+512] = __float2bfloat16((v2-mean)*rstd*g[t+512] + bb[t+512]);
}

// ======= fused residual(+split-K partials)(+bias) + LayerNorm, float4 ==========
__global__ __launch_bounds__(192) void ln_fuse(
    const float* __restrict__ hin, const float* __restrict__ Pp,
    const float* __restrict__ bias, const float* __restrict__ g,
    const float* __restrict__ bb, float* __restrict__ hout, bf16* __restrict__ xout)
{
    const int r = blockIdx.x;
    const int t = threadIdx.x;
    const int lane = t & 63, wv = t >> 6;
    const size_t base4 = (size_t)r * 192 + t;
    float4 v = ((const float4*)hin)[base4];
    const float4 p0 = ((const float4*)Pp)[base4];
    const float4 p1 = ((const float4*)Pp)[(size_t)TOKC * 192 + base4];
    v.x += p0.x + p1.x; v.y += p0.y + p1.y; v.z += p0.z + p1.z; v.w += p0.w + p1.w;
    if (bias) {
        const float4 bv = ((const float4*)bias)[t];
        v.x += bv.x; v.y += bv.y; v.z += bv.z; v.w += bv.w;
    }
    float s  = v.x + v.y + v.z + v.w;
    float ss = v.x*v.x + v.y*v.y + v.z*v.z + v.w*v.w;
#pragma unroll
    for (int off = 32; off >= 1; off >>= 1) {
        s  += __shfl_xor(s, off);
        ss += __shfl_xor(ss, off);
    }
    __shared__ float ws_[3][2];
    if (lane == 0) { ws_[wv][0] = s; ws_[wv][1] = ss; }
    __syncthreads();
    const float S  = ws_[0][0] + ws_[1][0] + ws_[2][0];
    const float SS = ws_[0][1] + ws_[1][1] + ws_[2][1];
    const float mean = S * (1.f/768.f);
    const float var  = SS * (1.f/768.f) - mean*mean;
    const float rstd = rsqrtf(var + EPSF);
    ((float4*)hout)[base4] = v;
    const float4 gg = ((const float4*)g)[t];
    const float4 bv2 = ((const float4*)bb)[t];
    bf16 tmp[4];
    tmp[0] = __float2bfloat16((v.x-mean)*rstd*gg.x + bv2.x);
    tmp[1] = __float2bfloat16((v.y-mean)*rstd*gg.y + bv2.y);
    tmp[2] = __float2bfloat16((v.z-mean)*rstd*gg.z + bv2.z);
    tmp[3] = __float2bfloat16((v.w-mean)*rstd*gg.w + bv2.w);
    *(uint2*)(xout + base4 * 4) = *(uint2*)tmp;
}

// ============ fused one-time setup: conv_w convert + cls row + lambda ==========
__global__ void setup_misc(const float* __restrict__ conv_w, bf16* __restrict__ cwbf,
                           const float* __restrict__ cls, const float* __restrict__ pos,
                           float* __restrict__ h,
                           const float* __restrict__ lq1, const float* __restrict__ lk1,
                           const float* __restrict__ lq2, const float* __restrict__ lk2,
                           float* __restrict__ lam)
{
    const int bid = blockIdx.x;
    if (bid < 2304) {
        const int i = bid * 256 + threadIdx.x;
        cwbf[i] = __float2bfloat16(conv_w[i]);
    } else if (bid < 2352) {
        const int i = (bid - 2304) * 256 + threadIdx.x;
        const int b_ = i / EE, e_ = i % EE;
        h[(size_t)(b_*NT)*EE + e_] = cls[e_] + pos[e_];
    } else {
        const int i = threadIdx.x;
        if (i < ND*HH) {
            float d1 = 0.f, d2 = 0.f;
            for (int d = 0; d < 64; ++d) {
                d1 += lq1[i*64+d]*lk1[i*64+d];
                d2 += lq2[i*64+d]*lk2[i*64+d];
            }
            lam[i] = expf(d1) - expf(d2) + LAMINIT;
        }
    }
}

__global__ void im2col_kernel(const float* __restrict__ x, bf16* __restrict__ xcol)
{
    const int i = blockIdx.x*256 + threadIdx.x;
    if (i >= 3136*EE) return;
    const int kidx = i % EE;
    const int p_ = i / EE;
    const int b_ = p_ / 196;
    const int pp = p_ % 196;
    const int gh = pp / 14, gw = pp % 14;
    const int c_ = kidx >> 8, rr = (kidx >> 4) & 15, q_ = kidx & 15;
    xcol[i] = __float2bfloat16(x[((size_t)(b_*3 + c_)*224 + gh*16 + rr)*224 + gw*16 + q_]);
}

// ====== all-layer weight transpose (f32[K][N] -> bf16[N][K]) — FROZEN ==========
// Six structural variants all measure ~100us (~2.2 TB/s); the limiter is below
// counter visibility (mixed-stream DRAM behavior). Keeping round-6 version.
__global__ __launch_bounds__(256) void transpose_pack(
    const float* __restrict__ Wq, const float* __restrict__ Wk,
    const float* __restrict__ Wv, const float* __restrict__ Wo,
    const float* __restrict__ W1, const float* __restrict__ W2,
    bf16* __restrict__ wall)
{
    __shared__ __align__(16) float tin[128 * 64];     // 32 KB
    __shared__ __align__(16) bf16  tout[64 * 384];    // 48 KB
    int bid = blockIdx.x;
    const int dl = bid / 384; bid -= dl * 384;
    bf16* wq_t = wall + (size_t)dl * 9437184;
    bf16* wo_t = wq_t + 3538944;
    bf16* w1_t = wo_t + 1179648;
    bf16* w2_t = w1_t + 2359296;
    const float* src; bf16* dst; int srcN, dstK, n0, k0;
    if (bid < 144) {                  // Q/K/V: 3 x (24 n-panels x 2 k-panels)
        const int z = bid / 48; const int r = bid - z * 48;
        src = (z == 0 ? Wq : (z == 1 ? Wk : Wv)) + (size_t)dl * EE * E2;
        dst = wq_t + (size_t)z * E2 * EE;
        srcN = E2; dstK = EE;
        n0 = (r >> 1) * 64; k0 = (r & 1) * 384;
    } else if (bid < 192) {           // Wo: 12 n-panels x 4 k-panels
        const int r = bid - 144;
        src = Wo + (size_t)dl * E2 * EE; dst = wo_t;
        srcN = EE; dstK = E2;
        n0 = (r >> 2) * 64; k0 = (r & 3) * 384;
    } else if (bid < 288) {           // W1: 48 n-panels x 2 k-panels
        const int r = bid - 192;
        src = W1 + (size_t)dl * EE * MLPD; dst = w1_t;
        srcN = MLPD; dstK = EE;
        n0 = (r >> 1) * 64; k0 = (r & 1) * 384;
    } else {                          // W2: 12 n-panels x 8 k-panels
        const int r = bid - 288;
        src = W2 + (size_t)dl * MLPD * EE; dst = w2_t;
        srcN = EE; dstK = MLPD;
        n0 = (r >> 3) * 64; k0 = (r & 7) * 384;
    }
    const int t = threadIdx.x;
    const int c = t & 63, kq = t >> 6;        // gather: col c, k-quarter kq

    for (int sub = 0; sub < 3; ++sub) {
        {
            const int row16 = t >> 4, nc = (t & 15) * 4;
            char* ldsb = (char*)tin;
#pragma unroll
            for (int i = 0; i < 8; ++i) {
                const int kr = i * 16 + row16;
                gld16(src + (size_t)(k0 + sub * 128 + kr) * srcN + n0 + nc,
                      ldsb + kr * 256 + (t & 15) * 16);
            }
        }
        asm volatile("s_waitcnt vmcnt(0)" ::: "memory");
        __syncthreads();
        bf16 a[32];
#pragma unroll
        for (int j = 0; j < 32; ++j)
            a[j] = __float2bfloat16(tin[(kq * 32 + j) * 64 + c]);
#pragma unroll
        for (int m = 0; m < 4; ++m) {
            const int kchunk = sub * 16 + kq * 4 + m;               // 0..47
            const int phys = (kchunk & ~7) | ((kchunk ^ c) & 7);
            *(uint4*)((char*)tout + c * 768 + phys * 16) = *(uint4*)&a[m * 8];
        }
        __syncthreads();
    }

#pragma unroll
    for (int it = 0; it < 12; ++it) {
        const int idx = it * 256 + t;
        const int r = idx / 48, ch = idx - r * 48;
        const int phys = (ch & ~7) | ((ch ^ r) & 7);
        *(uint4*)(dst + (size_t)(n0 + r) * dstK + k0 + ch * 8) =
            *(uint4*)((char*)tout + r * 768 + phys * 16);
    }
}

// ================= final LN (CLS rows, f32) =================
__global__ __launch_bounds__(256) void ln_cls(
    const float* __restrict__ h, const float* __restrict__ g,
    const float* __restrict__ bb, float* __restrict__ xr)
{
    const int b_ = blockIdx.x;
    const int t = threadIdx.x;
    const float* x = h + (size_t)(b_*NT)*EE;
    const float v0 = x[t], v1 = x[t+256], v2 = x[t+512];
    __shared__ float rs[256], rss[256];
    rs[t]  = v0+v1+v2;
    rss[t] = v0*v0+v1*v1+v2*v2;
    __syncthreads();
    for (int st = 128; st > 0; st >>= 1) {
        if (t < st) { rs[t] += rs[t+st]; rss[t] += rss[t+st]; }
        __syncthreads();
    }
    const float mean = rs[0] * (1.f/768.f);
    const float var  = rss[0] * (1.f/768.f) - mean*mean;
    const float rstd = rsqrtf(var + EPSF);
    float* o = xr + (size_t)b_ * EE;
    o[t]     = (v0-mean)*rstd*g[t]     + bb[t];
    o[t+256] = (v1-mean)*rstd*g[t+256] + bb[t+256];
    o[t+512] = (v2-mean)*rstd*g[t+512] + bb[t+512];
}

// ================= parallel classifier head =================
__global__ __launch_bounds__(256) void head_gemm(
    const float* __restrict__ xr, const float* __restrict__ hw,
    const float* __restrict__ hb, float* __restrict__ logits)
{
    const int b_ = blockIdx.y, ct = blockIdx.x;
    const int t = threadIdx.x;
    const int c_loc = t & 63, kp = t >> 6;
    const int c = ct * 64 + c_loc;
    __shared__ float xs[768];
    for (int i = t; i < 768; i += 256) xs[i] = xr[(size_t)b_*EE + i];
    __syncthreads();
    float acc = 0.f;
    if (c < NCLS) {
        const int k0 = kp * 192;
        for (int kk = k0; kk < k0 + 192; ++kk)
            acc += xs[kk] * hw[(size_t)kk * NCLS + c];
    }
    __shared__ float red[4][64];
    red[kp][c_loc] = acc;
    __syncthreads();
    if (kp == 0 && c < NCLS)
        logits[(size_t)b_*NCLS + c] =
            red[0][c_loc] + red[1][c_loc] + red[2][c_loc] + red[3][c_loc] + hb[c];
}

extern "C" void kernel_launch(void* const* d_in, const int* in_sizes, int n_in,
                              void* d_out, int out_size, void* d_ws, size_t ws_size,
                              hipStream_t stream)
{
    const float* x      = (const float*)d_in[0];
    const float* conv_w = (const float*)d_in[1];
    const float* conv_b = (const float*)d_in[2];
    const float* cls    = (const float*)d_in[3];
    const float* pos    = (const float*)d_in[4];
    const float* Wq     = (const float*)d_in[5];
    const float* Wk     = (const float*)d_in[6];
    const float* Wv     = (const float*)d_in[7];
    const float* lq1    = (const float*)d_in[8];
    const float* lk1    = (const float*)d_in[9];
    const float* lq2    = (const float*)d_in[10];
    const float* lk2    = (const float*)d_in[11];
    const float* gn_g   = (const float*)d_in[12];
    const float* gn_b   = (const float*)d_in[13];
    const float* Wo     = (const float*)d_in[14];
    const float* ln1_g  = (const float*)d_in[15];
    const float* ln1_b  = (const float*)d_in[16];
    const float* ln2_g  = (const float*)d_in[17];
    const float* ln2_b  = (const float*)d_in[18];
    const float* mlp_w1 = (const float*)d_in[19];
    const float* mlp_b1 = (const float*)d_in[20];
    const float* mlp_w2 = (const float*)d_in[21];
    const float* mlp_b2 = (const float*)d_in[22];
    const float* lnf_g  = (const float*)d_in[23];
    const float* lnf_b  = (const float*)d_in[24];
    const float* head_w = (const float*)d_in[25];
    const float* head_b = (const float*)d_in[26];

    float* out_f    = (float*)d_out;
    float* logits   = out_f;
    float* attn_out = out_f + (size_t)BB*NCLS;

    const int TOK = TOKC;
    const size_t TOKE = (size_t)TOK*EE;

    float* ws   = (float*)d_ws;
    float* h    = ws;
    float* o    = h + TOKE;
    float* Pp   = o + (size_t)BB*HH*NT*128;
    bf16*  Qrm  = (bf16*)(Pp + 2*TOKE);
    bf16*  Krm  = Qrm + (size_t)192*208*128;
    bf16*  Vf   = Krm + (size_t)192*208*128;
    bf16*  act2 = Vf + (size_t)192*7*8*512;
    bf16*  xn   = act2 + (size_t)TOK*MLPD;
    bf16*  wall = xn + TOKE;
    bf16*  cwbf = wall + (size_t)6*9437184;
    float* lam  = (float*)(cwbf + (size_t)EE*EE);
    float* xr   = lam + 128;
    float* gnst = xr + (size_t)BB*EE;

    hipMemsetAsync(Vf, 0, (size_t)192*7*8*512*2, stream);

    setup_misc<<<2353, 256, 0, stream>>>(conv_w, cwbf, cls, pos, h,
                                         lq1, lk1, lq2, lk2, lam);
    transpose_pack<<<6*384, 256, 0, stream>>>(Wq, Wk, Wv, Wo, mlp_w1, mlp_w2, wall);
    im2col_kernel<<<(3136*EE+255)/256, 256, 0, stream>>>(x, xn);
    gemm_bf16<<<dim3(EE/128, 25), 256, 0, stream>>>(
        xn, cwbf, conv_b, h, nullptr, nullptr, pos, 3136, EE, EE, EE, EE, 4);

    ln_rows<<<TOK, 256, 0, stream>>>(h, ln1_g, ln1_b, xn);

    for (int dl = 0; dl < ND; ++dl) {
        bf16* wq_t = wall + (size_t)dl*9437184;
        bf16* wo_t = wq_t + 3538944;
        bf16* w1_t = wo_t + 1179648;
        bf16* w2_t = w1_t + 2359296;

        gemm256t<4><<<dim3(4608/256, (TOK+255)/256), 512, 0, stream>>>(
            xn, wq_t, nullptr, (float*)Qrm, (float*)Krm, (float*)Vf,
            TOK, EE, 4608, 1);
        attn_mfma<<<2496, 64, 0, stream>>>(
            Qrm, Krm, Vf, lam + dl*HH, attn_out + (size_t)dl*BB*HH*NT*NT, o, gnst);
        gn_apply<<<dim3(4, BB*HH), 256, 0, stream>>>(
            o, gnst, gn_g + dl*128, gn_b + dl*128, act2);
        gemm_bf16<<<dim3(EE/128, 25, 2), 256, 0, stream>>>(
            act2, wo_t, nullptr, Pp, nullptr, nullptr, nullptr,
            TOK, E2/2, E2, E2, EE, 0);
        ln_fuse<<<TOK, 192, 0, stream>>>(
            h, Pp, nullptr, ln2_g + dl*EE, ln2_b + dl*EE, h, xn);
        gemm256t<3><<<dim3(MLPD/192, (TOK+255)/256), 512, 0, stream>>>(
            xn, w1_t, mlp_b1 + dl*MLPD, (float*)act2, nullptr, nullptr,
            TOK, EE, MLPD, 3);
        gemm_bf16<<<dim3(EE/128, 25, 2), 256, 0, stream>>>(
            act2, w2_t, nullptr, Pp, nullptr, nullptr, nullptr,
            TOK, MLPD/2, MLPD, MLPD, EE, 0);
        if (dl < ND-1)
            ln_fuse<<<TOK, 192, 0, stream>>>(
                h, Pp, mlp_b2 + dl*EE, ln1_g + (dl+1)*EE, ln1_b + (dl+1)*EE, h, xn);
        else
            ln_fuse<<<TOK, 192, 0, stream>>>(
                h, Pp, mlp_b2 + dl*EE, lnf_g, lnf_b, h, xn);
    }

    ln_cls<<<BB, 256, 0, stream>>>(h, lnf_g, lnf_b, xr);
    head_gemm<<<dim3(16, BB), 256, 0, stream>>>(xr, head_w, head_b, logits);
}

// Round 8
// 1379.364 us; speedup vs baseline: 1.1260x; 1.1260x over previous
//
#include <hip/hip_runtime.h>
#include <hip/hip_bf16.h>
#include <math.h>

#define BB 16
#define NT 197
#define EE 768
#define HH 12
#define E2 1536
#define MLPD 3072
#define NCLS 1000
#define ND 6
#define EPSF 1e-5f
#define SCALEF 0.125f
#define LAMINIT 0.8f
#define TOKC 3152

using v8bf  = __attribute__((ext_vector_type(8))) __bf16;
using f32x4 = __attribute__((ext_vector_type(4))) float;
typedef __hip_bfloat16 bf16;

#define AS1 __attribute__((address_space(1)))
#define AS3 __attribute__((address_space(3)))

__device__ __forceinline__ void gld16(const void* g, void* l) {
    __builtin_amdgcn_global_load_lds((const AS1 void*)g, (AS3 void*)l, 16, 0, 0);
}

__device__ __forceinline__ float gelu_f(float x) {
    const float u = x + 0.044715f * x * x * x;
    const float e = __expf(fminf(1.5957691216f * u, 80.f));
    return x * e / (e + 1.f);
}

// ================= bf16 MFMA GEMM: C[M][N] = A[M][K] @ Wt[N][K]^T =================
// 128x128 tile, BK=64, 256 threads (4 waves 2x2), wave 64x64 (4x4 frags).
// Kept for small-N shapes (conv mode 4, Wo/MLP2 mode 0 with split-K).
__global__ __launch_bounds__(256) void gemm_bf16(
    const bf16* __restrict__ A, const bf16* __restrict__ Wt,
    const float* __restrict__ bias, float* __restrict__ C0,
    float* __restrict__ C1, float* __restrict__ C2,
    const float* __restrict__ pos, int M, int K, int ldA, int ldB, int Nc, int mode)
{
    __shared__ __align__(16) unsigned char smem[32768];
    const int t = threadIdx.x;
    const int wave = t >> 6, lane = t & 63;
    const int wr = wave >> 1, wc = wave & 1;
    const int lr = lane & 15, lk = lane >> 4;

    const int bid0 = blockIdx.y * gridDim.x + blockIdx.x;
    const int nwg = gridDim.x * gridDim.y;
    const int qv = nwg >> 3, rv = nwg & 7;
    const int xcd = bid0 & 7, ii = bid0 >> 3;
    const int wgid = (xcd < rv ? xcd * (qv + 1) : rv * (qv + 1) + (xcd - rv) * qv) + ii;
    const int rowBase = (wgid / gridDim.x) * 128;
    const int colBase = (wgid % gridDim.x) * 128;
    const size_t zoff = (size_t)blockIdx.z * K * 2;

    f32x4 acc[4][4];
#pragma unroll
    for (int i = 0; i < 4; ++i)
#pragma unroll
        for (int j = 0; j < 4; ++j) acc[i][j] = (f32x4){0.f,0.f,0.f,0.f};

    const size_t ldA2 = (size_t)ldA * 2, ldB2 = (size_t)ldB * 2;
    const int srow = t >> 3;
    const int schunk = (t & 7) ^ ((t >> 3) & 7);
    const char* Abase = (const char*)A + zoff + schunk * 16;
    const char* Bbase = (const char*)Wt + zoff + schunk * 16;
    unsigned char* lA = smem + t * 16;
    unsigned char* lB = smem + 16384 + t * 16;
    const v8bf* Sa = (const v8bf*)smem;
    const v8bf* Sb = (const v8bf*)(smem + 16384);

    int rA[4], rB[4];
#pragma unroll
    for (int c = 0; c < 4; ++c) {
        rA[c] = min(rowBase + c * 32 + srow, M - 1);
        rB[c] = colBase + c * 32 + srow;
    }

    for (int k0 = 0; k0 < K; k0 += 64) {
        const size_t kb = (size_t)k0 * 2;
#pragma unroll
        for (int c = 0; c < 4; ++c) {
            gld16(Abase + (size_t)rA[c] * ldA2 + kb, lA + c * 4096);
            gld16(Bbase + (size_t)rB[c] * ldB2 + kb, lB + c * 4096);
        }
        __syncthreads();
#pragma unroll
        for (int s = 0; s < 2; ++s) {
            const int xr_ = (s * 4 + lk) ^ (lr & 7);
            v8bf af[4], bfr[4];
#pragma unroll
            for (int i = 0; i < 4; ++i) af[i] = Sa[(wr * 64 + i * 16 + lr) * 8 + xr_];
#pragma unroll
            for (int j = 0; j < 4; ++j) bfr[j] = Sb[(wc * 64 + j * 16 + lr) * 8 + xr_];
#pragma unroll
            for (int i = 0; i < 4; ++i)
#pragma unroll
                for (int j = 0; j < 4; ++j)
                    acc[i][j] = __builtin_amdgcn_mfma_f32_16x16x32_bf16(af[i], bfr[j], acc[i][j], 0, 0, 0);
        }
        __syncthreads();
    }

    // ---------------- epilogues (smem reused) ----------------
    if (mode == 0) {
        float* Cs = (float*)smem;                 // [64][128]
        float* C0z = C0 + (size_t)blockIdx.z * M * Nc;
#pragma unroll
        for (int half = 0; half < 2; ++half) {
            __syncthreads();
            if (wr == half) {
#pragma unroll
                for (int i = 0; i < 4; ++i)
#pragma unroll
                    for (int j = 0; j < 4; ++j)
#pragma unroll
                        for (int rr = 0; rr < 4; ++rr)
                            Cs[(i*16 + lk*4 + rr)*128 + wc*64 + j*16 + lr] = acc[i][j][rr];
            }
            __syncthreads();
#pragma unroll
            for (int k = 0; k < 8; ++k) {
                const int idx = k*256 + t;
                const int row = idx >> 5, c4 = idx & 31;
                const int r = rowBase + half*64 + row;
                if (r < M)
                    *(float4*)&C0z[(size_t)r*Nc + colBase + c4*4] = *(float4*)&Cs[row*128 + c4*4];
            }
        }
    } else if (mode == 1) {
        const int which = colBase / E2;
        if (which == 2) {
#pragma unroll
            for (int i = 0; i < 4; ++i)
#pragma unroll
                for (int j = 0; j < 4; ++j)
#pragma unroll
                    for (int rr = 0; rr < 4; ++rr) {
                        const int r = rowBase + wr * 64 + i * 16 + lk * 4 + rr;
                        const int c = colBase + wc * 64 + j * 16 + lr;
                        if (r >= M) continue;
                        const int b_ = r / NT, n_ = r % NT;
                        const int cc = c % E2;
                        const int h_ = cc >> 7, d_ = cc & 127;
                        const size_t bh = (size_t)(b_ * HH + h_);
                        ((bf16*)C2)[((bh * 7 + (n_ >> 5)) * 8 + (d_ >> 4)) * 512 +
                                    (size_t)(((d_ & 15) + (((n_ >> 3) & 3) << 4)) * 8 + (n_ & 7))] =
                            __float2bfloat16(acc[i][j][rr]);
                    }
        } else {
            const int hFix = (colBase % E2) >> 7;
            bf16* dstBase = (bf16*)(which == 0 ? C0 : C1);
            bf16* Cs = (bf16*)smem;               // [128][128]
            __syncthreads();
#pragma unroll
            for (int i = 0; i < 4; ++i)
#pragma unroll
                for (int j = 0; j < 4; ++j)
#pragma unroll
                    for (int rr = 0; rr < 4; ++rr)
                        Cs[(wr*64 + i*16 + lk*4 + rr)*128 + wc*64 + j*16 + lr] =
                            __float2bfloat16(acc[i][j][rr]);
            __syncthreads();
#pragma unroll
            for (int k = 0; k < 8; ++k) {
                const int idx = k*256 + t;
                const int row = idx >> 4, c8 = idx & 15;
                const int r = rowBase + row;
                if (r < M) {
                    const int b_ = r / NT, n_ = r - b_ * NT;
                    const size_t bh = (size_t)(b_ * HH + hFix);
                    *(uint4*)(dstBase + (bh * 208 + n_) * 128 + c8 * 8) =
                        *(uint4*)&Cs[row*128 + c8*8];
                }
            }
        }
    } else if (mode == 3) {
        bf16* Cs = (bf16*)smem;                   // [128][128]
        __syncthreads();
#pragma unroll
        for (int i = 0; i < 4; ++i)
#pragma unroll
            for (int j = 0; j < 4; ++j)
#pragma unroll
                for (int rr = 0; rr < 4; ++rr) {
                    const int c = colBase + wc*64 + j*16 + lr;
                    float val = acc[i][j][rr] + bias[c];
                    Cs[(wr*64 + i*16 + lk*4 + rr)*128 + wc*64 + j*16 + lr] =
                        __float2bfloat16(gelu_f(val));
                }
        __syncthreads();
        bf16* C0b = (bf16*)C0;
#pragma unroll
        for (int k = 0; k < 8; ++k) {
            const int idx = k*256 + t;
            const int row = idx >> 4, c8 = idx & 15;
            const int r = rowBase + row;
            if (r < M)
                *(uint4*)(C0b + (size_t)r*Nc + colBase + c8*8) = *(uint4*)&Cs[row*128 + c8*8];
        }
    } else { // mode 4: patch scatter
#pragma unroll
        for (int i = 0; i < 4; ++i)
#pragma unroll
            for (int j = 0; j < 4; ++j)
#pragma unroll
                for (int rr = 0; rr < 4; ++rr) {
                    const int r = rowBase + wr * 64 + i * 16 + lk * 4 + rr;
                    const int c = colBase + wc * 64 + j * 16 + lr;
                    if (r >= M) continue;
                    const int b_ = r / 196, p_ = r % 196;
                    C0[((size_t)(b_ * NT) + 1 + p_) * EE + c] =
                        acc[i][j][rr] + bias[c] + pos[(size_t)(1 + p_) * EE + c];
                }
    }
}

// ================= 256xNB-tile deep-pipelined bf16 GEMM (8 waves) ==============
// BM=256, BN=NF*64 (NF=4: 256 wide, NF=3: 192 wide for MLP1 grid coverage).
// 512 threads (2M x 4N waves), wave computes 128 x NF*16 frags.
// LDS double-buffered (A 32KB + B NF*8KB per buf), chunk-XOR swizzle both-sides.
// Counted vmcnt (never 0 in steady state), raw s_barrier, setprio around MFMA.
// 2-phase schedule (round-2 best; 4-phase variant measured WORSE — barrier cost).
// V-epilogue: register scatter (round-7 LDS-packed variant measured WORSE:
// +170us — the pack loop was serial LDS work exceeding the scatter cost).
// modes: 1 = QKV scatter (NF=4 only), 3 = bias+gelu bf16.
template<int NF>
__global__ __launch_bounds__(512, 2) void gemm256t(
    const bf16* __restrict__ A, const bf16* __restrict__ Wt,
    const float* __restrict__ bias, float* __restrict__ C0,
    float* __restrict__ C1, float* __restrict__ C2,
    int M, int K, int Nc, int mode)
{
    constexpr int NB = NF * 64;
    constexpr int BUFSZ = 32768 + NF * 8192;
    __shared__ __align__(16) unsigned char smem[2 * BUFSZ];
    const int t = threadIdx.x;
    const int wave = t >> 6, lane = t & 63;
    const int wm = wave >> 2, wn = wave & 3;
    const int lr = lane & 15, lk = lane >> 4;

    const int bid0 = blockIdx.y * gridDim.x + blockIdx.x;
    const int nwg = gridDim.x * gridDim.y;
    const int qv = nwg >> 3, rv = nwg & 7;
    const int xcd = bid0 & 7, ii = bid0 >> 3;
    const int wgid = (xcd < rv ? xcd * (qv + 1) : rv * (qv + 1) + (xcd - rv) * qv) + ii;
    const int rowBase = (wgid / gridDim.x) * 256;
    const int colBase = (wgid % gridDim.x) * NB;

    f32x4 acc[8][NF];
#pragma unroll
    for (int i = 0; i < 8; ++i)
#pragma unroll
        for (int j = 0; j < NF; ++j) acc[i][j] = (f32x4){0.f,0.f,0.f,0.f};

    const size_t ldK2 = (size_t)K * 2;
    const int srow = t >> 3;                       // 0..63
    const int schunk = (t & 7) ^ (srow & 7);       // pre-swizzled global chunk
    const char* Abase = (const char*)A + schunk * 16;
    const char* Bbase = (const char*)Wt + schunk * 16;

    int rA[4], rB[NF];
#pragma unroll
    for (int p = 0; p < 4; ++p) rA[p] = min(rowBase + p * 64 + srow, M - 1);
#pragma unroll
    for (int p = 0; p < NF; ++p) rB[p] = colBase + p * 64 + srow;

    // ---- prologue: stage tile0 -> buf0, tile1 -> buf1 ----
    {
        unsigned char* l0 = smem + t * 16;
#pragma unroll
        for (int p = 0; p < 4; ++p) gld16(Abase + (size_t)rA[p] * ldK2, l0 + p * 8192);
#pragma unroll
        for (int p = 0; p < NF; ++p) gld16(Bbase + (size_t)rB[p] * ldK2, l0 + 32768 + p * 8192);
#pragma unroll
        for (int p = 0; p < 4; ++p) gld16(Abase + (size_t)rA[p] * ldK2 + 128, l0 + BUFSZ + p * 8192);
#pragma unroll
        for (int p = 0; p < NF; ++p) gld16(Bbase + (size_t)rB[p] * ldK2 + 128, l0 + BUFSZ + 32768 + p * 8192);
        if constexpr (NF == 4) asm volatile("s_waitcnt vmcnt(8)" ::: "memory");
        else                   asm volatile("s_waitcnt vmcnt(7)" ::: "memory");
        asm volatile("s_barrier" ::: "memory");
    }

    const int NTt = K >> 6;
    for (int kt = 0; kt < NTt; ++kt) {
        const int buf = kt & 1;
        const v8bf* Sa = (const v8bf*)(smem + buf * BUFSZ);
        const v8bf* Sb = (const v8bf*)(smem + buf * BUFSZ + 32768);

        // ---- phase A: read B(all) + A(half0), MFMA quadrant mh=0 ----
        v8bf bfr[2][NF], af[2][4];
#pragma unroll
        for (int s = 0; s < 2; ++s) {
            const int x0 = s * 4 + lk;
#pragma unroll
            for (int j = 0; j < NF; ++j) {
                const int row = wn * (NF * 16) + j * 16 + lr;
                bfr[s][j] = Sb[row * 8 + (x0 ^ (lr & 7))];
            }
#pragma unroll
            for (int i = 0; i < 4; ++i) {
                const int row = wm * 128 + i * 16 + lr;
                af[s][i] = Sa[row * 8 + (x0 ^ (lr & 7))];
            }
        }
        __builtin_amdgcn_s_setprio(1);
#pragma unroll
        for (int s = 0; s < 2; ++s)
#pragma unroll
            for (int i = 0; i < 4; ++i)
#pragma unroll
                for (int j = 0; j < NF; ++j)
                    acc[i][j] = __builtin_amdgcn_mfma_f32_16x16x32_bf16(af[s][i], bfr[s][j], acc[i][j], 0, 0, 0);
        __builtin_amdgcn_s_setprio(0);

        // ---- phase B: read A(half1), release buf, prefetch kt+2, MFMA mh=1 ----
        v8bf af2[2][4];
#pragma unroll
        for (int s = 0; s < 2; ++s)
#pragma unroll
            for (int i = 0; i < 4; ++i) {
                const int row = wm * 128 + 64 + i * 16 + lr;
                af2[s][i] = Sa[row * 8 + ((s * 4 + lk) ^ (lr & 7))];
            }
        asm volatile("s_waitcnt lgkmcnt(0)" ::: "memory");   // my reads of buf done
        asm volatile("s_barrier" ::: "memory");              // all waves done reading buf
        if (kt + 2 < NTt) {
            const size_t kb = (size_t)(kt + 2) * 128;
            unsigned char* ld = smem + buf * BUFSZ + t * 16;
#pragma unroll
            for (int p = 0; p < 4; ++p) gld16(Abase + (size_t)rA[p] * ldK2 + kb, ld + p * 8192);
#pragma unroll
            for (int p = 0; p < NF; ++p) gld16(Bbase + (size_t)rB[p] * ldK2 + kb, ld + 32768 + p * 8192);
            if constexpr (NF == 4) asm volatile("s_waitcnt vmcnt(8)" ::: "memory");
            else                   asm volatile("s_waitcnt vmcnt(7)" ::: "memory");
        } else {
            asm volatile("s_waitcnt vmcnt(0)" ::: "memory"); // drain tail
        }
        asm volatile("s_barrier" ::: "memory");              // everyone's kt+1 landed
        __builtin_amdgcn_s_setprio(1);
#pragma unroll
        for (int s = 0; s < 2; ++s)
#pragma unroll
            for (int i = 0; i < 4; ++i)
#pragma unroll
                for (int j = 0; j < NF; ++j)
                    acc[4 + i][j] = __builtin_amdgcn_mfma_f32_16x16x32_bf16(af2[s][i], bfr[s][j], acc[4 + i][j], 0, 0, 0);
        __builtin_amdgcn_s_setprio(0);
    }

    // ---------------- epilogues (smem reused) ----------------
    if constexpr (NF == 4) {
        if (mode == 1) {
            const int which = colBase / E2;
            if (which == 2) {
                // V: fragment-major register scatter
#pragma unroll
                for (int i = 0; i < 8; ++i)
#pragma unroll
                    for (int j = 0; j < 4; ++j)
#pragma unroll
                        for (int rr = 0; rr < 4; ++rr) {
                            const int r = rowBase + wm * 128 + i * 16 + lk * 4 + rr;
                            if (r >= M) continue;
                            const int c = colBase + wn * 64 + j * 16 + lr;
                            const int b_ = r / NT, n_ = r % NT;
                            const int cc = c % E2;
                            const int h_ = cc >> 7, d_ = cc & 127;
                            const size_t bh = (size_t)(b_ * HH + h_);
                            ((bf16*)C2)[((bh * 7 + (n_ >> 5)) * 8 + (d_ >> 4)) * 512 +
                                        (size_t)(((d_ & 15) + (((n_ >> 3) & 3) << 4)) * 8 + (n_ & 7))] =
                                __float2bfloat16(acc[i][j][rr]);
                        }
            } else {
                bf16* dstBase = (bf16*)(which == 0 ? C0 : C1);
                const int h0 = (colBase % E2) >> 7;   // tile spans heads h0, h0+1
                bf16* Cs = (bf16*)smem;               // [256][256]
                __syncthreads();
#pragma unroll
                for (int i = 0; i < 8; ++i)
#pragma unroll
                    for (int j = 0; j < 4; ++j)
#pragma unroll
                        for (int rr = 0; rr < 4; ++rr)
                            Cs[(wm*128 + i*16 + lk*4 + rr)*256 + wn*64 + j*16 + lr] =
                                __float2bfloat16(acc[i][j][rr]);
                __syncthreads();
#pragma unroll
                for (int k = 0; k < 16; ++k) {
                    const int idx = k * 512 + t;
                    const int row = idx >> 5, c8 = idx & 31;
                    const int r = rowBase + row;
                    if (r < M) {
                        const int b_ = r / NT, n_ = r - b_ * NT;
                        const size_t bh = (size_t)(b_ * HH + h0 + (c8 >> 4));
                        *(uint4*)(dstBase + (bh * 208 + n_) * 128 + (size_t)(c8 & 15) * 8) =
                            *(uint4*)&Cs[row * 256 + c8 * 8];
                    }
                }
            }
            return;
        }
    }
    { // mode 3: bias + gelu -> bf16 row-major
        bf16* Cs = (bf16*)smem;                   // [256][NB]
        __syncthreads();
#pragma unroll
        for (int i = 0; i < 8; ++i)
#pragma unroll
            for (int j = 0; j < NF; ++j) {
                const int c = colBase + wn * (NF * 16) + j * 16 + lr;
                const float bv = bias[c];
#pragma unroll
                for (int rr = 0; rr < 4; ++rr)
                    Cs[(wm*128 + i*16 + lk*4 + rr)*NB + wn*(NF*16) + j*16 + lr] =
                        __float2bfloat16(gelu_f(acc[i][j][rr] + bv));
            }
        __syncthreads();
        bf16* C0b = (bf16*)C0;
        constexpr int CW = NB / 8;                // uint4 chunks per row
        constexpr int ITER = 256 * CW / 512;
#pragma unroll
        for (int k = 0; k < ITER; ++k) {
            const int idx = k * 512 + t;
            const int row = idx / CW, c8 = idx - row * CW;
            const int r = rowBase + row;
            if (r < M)
                *(uint4*)(C0b + (size_t)r * Nc + colBase + c8 * 8) =
                    *(uint4*)&Cs[row * NB + c8 * 8];
        }
    }
}

// ================= MFMA differential attention: 1 wave per (bh, 16-q-rows) ====
__global__ __launch_bounds__(64) void attn_mfma(
    const bf16* __restrict__ Qrm, const bf16* __restrict__ Krm,
    const bf16* __restrict__ Vf, const float* __restrict__ lamp,
    float* __restrict__ aout, float* __restrict__ o, float* __restrict__ stats)
{
    const int lane = threadIdx.x;
    const int fid = blockIdx.x;
    const int xcd = fid & 7, rest = fid >> 3;
    const int qt = rest % 13, g = rest / 13;
    const int bh = g * 8 + xcd;
    const int hh = bh % HH;
    const int lr = lane & 15, lk = lane >> 4;

    __shared__ __align__(16) bf16 P[16][232];

    {
        const int r = lane & 15, c0 = 192 + (lane >> 4) * 10;
#pragma unroll
        for (int j = 0; j < 10; ++j) P[r][c0 + j] = __float2bfloat16(0.f);
    }

    v8bf qa[4];
    const bf16* Qb = Qrm + ((size_t)bh * 208 + qt * 16) * 128;
#pragma unroll
    for (int kk = 0; kk < 4; ++kk)
        qa[kk] = *(const v8bf*)(Qb + lr * 128 + kk * 32 + lk * 8);

    const bf16* Kb = Krm + (size_t)bh * 208 * 128;
    const f32x4 zf = {0.f, 0.f, 0.f, 0.f};
    f32x4 s1[13], s2[13];
#pragma unroll
    for (int t = 0; t < 13; ++t) {
        const bf16* Kt = Kb + (t * 16 + lr) * 128 + lk * 8;
        const v8bf k0 = *(const v8bf*)(Kt);
        const v8bf k1 = *(const v8bf*)(Kt + 32);
        const v8bf k2 = *(const v8bf*)(Kt + 64);
        const v8bf k3 = *(const v8bf*)(Kt + 96);
        s1[t] = __builtin_amdgcn_mfma_f32_16x16x32_bf16(qa[1], k1,
                __builtin_amdgcn_mfma_f32_16x16x32_bf16(qa[0], k0, zf, 0, 0, 0), 0, 0, 0);
        s2[t] = __builtin_amdgcn_mfma_f32_16x16x32_bf16(qa[3], k3,
                __builtin_amdgcn_mfma_f32_16x16x32_bf16(qa[2], k2, zf, 0, 0, 0), 0, 0, 0);
    }

    float m1[4] = {-1e30f,-1e30f,-1e30f,-1e30f}, m2[4] = {-1e30f,-1e30f,-1e30f,-1e30f};
#pragma unroll
    for (int t = 0; t < 13; ++t) {
        const bool kv = (t * 16 + lr) < NT;
#pragma unroll
        for (int rr = 0; rr < 4; ++rr) {
            s1[t][rr] = kv ? s1[t][rr] * SCALEF : -1e30f;
            s2[t][rr] = kv ? s2[t][rr] * SCALEF : -1e30f;
            m1[rr] = fmaxf(m1[rr], s1[t][rr]);
            m2[rr] = fmaxf(m2[rr], s2[t][rr]);
        }
    }
#pragma unroll
    for (int off = 8; off >= 1; off >>= 1)
#pragma unroll
        for (int rr = 0; rr < 4; ++rr) {
            m1[rr] = fmaxf(m1[rr], __shfl_xor(m1[rr], off));
            m2[rr] = fmaxf(m2[rr], __shfl_xor(m2[rr], off));
        }

    float z1[4] = {0,0,0,0}, z2[4] = {0,0,0,0};
#pragma unroll
    for (int t = 0; t < 13; ++t)
#pragma unroll
        for (int rr = 0; rr < 4; ++rr) {
            const float e1 = __expf(s1[t][rr] - m1[rr]);
            const float e2 = __expf(s2[t][rr] - m2[rr]);
            s1[t][rr] = e1; s2[t][rr] = e2;
            z1[rr] += e1; z2[rr] += e2;
        }
#pragma unroll
    for (int off = 8; off >= 1; off >>= 1)
#pragma unroll
        for (int rr = 0; rr < 4; ++rr) {
            z1[rr] += __shfl_xor(z1[rr], off);
            z2[rr] += __shfl_xor(z2[rr], off);
        }
    const float lam = lamp[hh];
    float r1[4], r2[4];
#pragma unroll
    for (int rr = 0; rr < 4; ++rr) { r1[rr] = 1.f / z1[rr]; r2[rr] = lam / z2[rr]; }

    __syncthreads();
#pragma unroll
    for (int t = 0; t < 13; ++t) {
        const int m_ = t * 16 + lr;
#pragma unroll
        for (int rr = 0; rr < 4; ++rr) {
            const float p = s1[t][rr] * r1[rr] - s2[t][rr] * r2[rr];
            const int n_ = lk * 4 + rr;
            P[n_][m_] = __float2bfloat16(p);
            const int n_g = qt * 16 + n_;
            if (m_ < NT && n_g < NT)
                aout[((size_t)bh * NT + n_g) * NT + m_] = p;
        }
    }
    __syncthreads();

    f32x4 oacc[8];
#pragma unroll
    for (int dt = 0; dt < 8; ++dt) oacc[dt] = zf;
    const v8bf* Vp = (const v8bf*)(Vf + (size_t)bh * 7 * 8 * 512);
    const bf16* Pb = &P[0][0];
#pragma unroll
    for (int mk = 0; mk < 7; ++mk) {
        const v8bf pa = *(const v8bf*)(Pb + lr * 232 + mk * 32 + lk * 8);
#pragma unroll
        for (int dt = 0; dt < 8; ++dt)
            oacc[dt] = __builtin_amdgcn_mfma_f32_16x16x32_bf16(
                pa, Vp[(mk * 8 + dt) * 64 + lane], oacc[dt], 0, 0, 0);
    }
#pragma unroll
    for (int dt = 0; dt < 8; ++dt)
#pragma unroll
        for (int rr = 0; rr < 4; ++rr) {
            const int n_g = qt * 16 + lk * 4 + rr;
            if (n_g < NT)
                o[((size_t)bh * NT + n_g) * 128 + dt * 16 + lr] = oacc[dt][rr];
        }

    float s = 0.f, ss = 0.f;
#pragma unroll
    for (int dt = 0; dt < 8; ++dt)
#pragma unroll
        for (int rr = 0; rr < 4; ++rr) {
            const int n_g = qt * 16 + lk * 4 + rr;
            const float vv = (n_g < NT) ? oacc[dt][rr] : 0.f;
            s += vv; ss += vv * vv;
        }
#pragma unroll
    for (int off = 32; off >= 1; off >>= 1) {
        s  += __shfl_xor(s, off);
        ss += __shfl_xor(ss, off);
    }
    if (lane == 0) {
        stats[(bh * 13 + qt) * 2]     = s;
        stats[(bh * 13 + qt) * 2 + 1] = ss;
    }
}

// ================= GN apply: normalize + relayout (b,n,2E) bf16 ================
__global__ __launch_bounds__(256) void gn_apply(
    const float* __restrict__ o, const float* __restrict__ stats,
    const float* __restrict__ g, const float* __restrict__ bb, bf16* __restrict__ o2)
{
    const int bh = blockIdx.y, qq = blockIdx.x;
    const int t = threadIdx.x;
    float S = 0.f, SS = 0.f;
#pragma unroll
    for (int j = 0; j < 13; ++j) {
        S  += stats[(bh * 13 + j) * 2];
        SS += stats[(bh * 13 + j) * 2 + 1];
    }
    const float inv = 1.f / (float)(NT * 128);
    const float mean = S * inv;
    const float var  = SS * inv - mean * mean;
    const float rstd = rsqrtf(var + EPSF);
    const int b_ = bh / HH, h_ = bh % HH;
    const float4* ob = (const float4*)(o + (size_t)bh * NT * 128);
    const float4* g4 = (const float4*)g;
    const float4* b4 = (const float4*)bb;
    for (int idx = t; idx < 50 * 32; idx += 256) {
        const int n_ = qq * 50 + (idx >> 5);
        if (n_ >= NT) continue;
        const int d4 = idx & 31;
        const float4 v4 = ob[n_ * 32 + d4];
        const float4 gg = g4[d4], bv = b4[d4];
        bf16 tmp[4];
        tmp[0] = __float2bfloat16((v4.x - mean) * rstd * gg.x + bv.x);
        tmp[1] = __float2bfloat16((v4.y - mean) * rstd * gg.y + bv.y);
        tmp[2] = __float2bfloat16((v4.z - mean) * rstd * gg.z + bv.z);
        tmp[3] = __float2bfloat16((v4.w - mean) * rstd * gg.w + bv.w);
        *(uint2*)(o2 + ((size_t)(b_ * NT + n_)) * E2 + h_ * 128 + d4 * 4) = *(uint2*)tmp;
    }
}

// ================= LayerNorm rows -> bf16 (layer 0 entry) =================
__global__ __launch_bounds__(256) void ln_rows(
    const float* __restrict__ in, const float* __restrict__ g,
    const float* __restrict__ bb, bf16* __restrict__ out)
{
    const int r = blockIdx.x;
    const int t = threadIdx.x;
    const float* x = in + (size_t)r * EE;
    const float v0 = x[t], v1 = x[t+256], v2 = x[t+512];
    __shared__ float rs[256], rss[256];
    rs[t]  = v0+v1+v2;
    rss[t] = v0*v0+v1*v1+v2*v2;
    __syncthreads();
    for (int st = 128; st > 0; st >>= 1) {
        if (t < st) { rs[t] += rs[t+st]; rss[t] += rss[t+st]; }
        __syncthreads();
    }
    const float mean = rs[0] * (1.f/768.f);
    const float var  = rss[0] * (1.f/768.f) - mean*mean;
    const float rstd = rsqrtf(var + EPSF);
    bf16* o = out + (size_t)r * EE;
    o[t]     = __float2bfloat16((v0-mean)*rstd*g[t]     + bb[t]);
    o[t+256] = __float2bfloat16((v1-mean)*rstd*g[t+256] + bb[t+256]);
    o[t+512] = __float2bfloat16((v2-mean)*rstd*g[t+512] + bb[t+512]);
}

// ======= fused residual(+split-K partials)(+bias) + LayerNorm, float4 ==========
__global__ __launch_bounds__(192) void ln_fuse(
    const float* __restrict__ hin, const float* __restrict__ Pp,
    const float* __restrict__ bias, const float* __restrict__ g,
    const float* __restrict__ bb, float* __restrict__ hout, bf16* __restrict__ xout)
{
    const int r = blockIdx.x;
    const int t = threadIdx.x;
    const int lane = t & 63, wv = t >> 6;
    const size_t base4 = (size_t)r * 192 + t;
    float4 v = ((const float4*)hin)[base4];
    const float4 p0 = ((const float4*)Pp)[base4];
    const float4 p1 = ((const float4*)Pp)[(size_t)TOKC * 192 + base4];
    v.x += p0.x + p1.x; v.y += p0.y + p1.y; v.z += p0.z + p1.z; v.w += p0.w + p1.w;
    if (bias) {
        const float4 bv = ((const float4*)bias)[t];
        v.x += bv.x; v.y += bv.y; v.z += bv.z; v.w += bv.w;
    }
    float s  = v.x + v.y + v.z + v.w;
    float ss = v.x*v.x + v.y*v.y + v.z*v.z + v.w*v.w;
#pragma unroll
    for (int off = 32; off >= 1; off >>= 1) {
        s  += __shfl_xor(s, off);
        ss += __shfl_xor(ss, off);
    }
    __shared__ float ws_[3][2];
    if (lane == 0) { ws_[wv][0] = s; ws_[wv][1] = ss; }
    __syncthreads();
    const float S  = ws_[0][0] + ws_[1][0] + ws_[2][0];
    const float SS = ws_[0][1] + ws_[1][1] + ws_[2][1];
    const float mean = S * (1.f/768.f);
    const float var  = SS * (1.f/768.f) - mean*mean;
    const float rstd = rsqrtf(var + EPSF);
    ((float4*)hout)[base4] = v;
    const float4 gg = ((const float4*)g)[t];
    const float4 bv2 = ((const float4*)bb)[t];
    bf16 tmp[4];
    tmp[0] = __float2bfloat16((v.x-mean)*rstd*gg.x + bv2.x);
    tmp[1] = __float2bfloat16((v.y-mean)*rstd*gg.y + bv2.y);
    tmp[2] = __float2bfloat16((v.z-mean)*rstd*gg.z + bv2.z);
    tmp[3] = __float2bfloat16((v.w-mean)*rstd*gg.w + bv2.w);
    *(uint2*)(xout + base4 * 4) = *(uint2*)tmp;
}

// ============ fused one-time setup: conv_w convert + cls row + lambda ==========
__global__ void setup_misc(const float* __restrict__ conv_w, bf16* __restrict__ cwbf,
                           const float* __restrict__ cls, const float* __restrict__ pos,
                           float* __restrict__ h,
                           const float* __restrict__ lq1, const float* __restrict__ lk1,
                           const float* __restrict__ lq2, const float* __restrict__ lk2,
                           float* __restrict__ lam)
{
    const int bid = blockIdx.x;
    if (bid < 2304) {
        const int i = bid * 256 + threadIdx.x;
        cwbf[i] = __float2bfloat16(conv_w[i]);
    } else if (bid < 2352) {
        const int i = (bid - 2304) * 256 + threadIdx.x;
        const int b_ = i / EE, e_ = i % EE;
        h[(size_t)(b_*NT)*EE + e_] = cls[e_] + pos[e_];
    } else {
        const int i = threadIdx.x;
        if (i < ND*HH) {
            float d1 = 0.f, d2 = 0.f;
            for (int d = 0; d < 64; ++d) {
                d1 += lq1[i*64+d]*lk1[i*64+d];
                d2 += lq2[i*64+d]*lk2[i*64+d];
            }
            lam[i] = expf(d1) - expf(d2) + LAMINIT;
        }
    }
}

__global__ void im2col_kernel(const float* __restrict__ x, bf16* __restrict__ xcol)
{
    const int i = blockIdx.x*256 + threadIdx.x;
    if (i >= 3136*EE) return;
    const int kidx = i % EE;
    const int p_ = i / EE;
    const int b_ = p_ / 196;
    const int pp = p_ % 196;
    const int gh = pp / 14, gw = pp % 14;
    const int c_ = kidx >> 8, rr = (kidx >> 4) & 15, q_ = kidx & 15;
    xcol[i] = __float2bfloat16(x[((size_t)(b_*3 + c_)*224 + gh*16 + rr)*224 + gw*16 + q_]);
}

// ====== all-layer weight transpose (f32[K][N] -> bf16[N][K]) — FROZEN ==========
// Six structural variants all measure ~100us (~2.2 TB/s); the limiter is below
// counter visibility (mixed-stream DRAM behavior). Keeping round-6 version.
__global__ __launch_bounds__(256) void transpose_pack(
    const float* __restrict__ Wq, const float* __restrict__ Wk,
    const float* __restrict__ Wv, const float* __restrict__ Wo,
    const float* __restrict__ W1, const float* __restrict__ W2,
    bf16* __restrict__ wall)
{
    __shared__ __align__(16) float tin[128 * 64];     // 32 KB
    __shared__ __align__(16) bf16  tout[64 * 384];    // 48 KB
    int bid = blockIdx.x;
    const int dl = bid / 384; bid -= dl * 384;
    bf16* wq_t = wall + (size_t)dl * 9437184;
    bf16* wo_t = wq_t + 3538944;
    bf16* w1_t = wo_t + 1179648;
    bf16* w2_t = w1_t + 2359296;
    const float* src; bf16* dst; int srcN, dstK, n0, k0;
    if (bid < 144) {                  // Q/K/V: 3 x (24 n-panels x 2 k-panels)
        const int z = bid / 48; const int r = bid - z * 48;
        src = (z == 0 ? Wq : (z == 1 ? Wk : Wv)) + (size_t)dl * EE * E2;
        dst = wq_t + (size_t)z * E2 * EE;
        srcN = E2; dstK = EE;
        n0 = (r >> 1) * 64; k0 = (r & 1) * 384;
    } else if (bid < 192) {           // Wo: 12 n-panels x 4 k-panels
        const int r = bid - 144;
        src = Wo + (size_t)dl * E2 * EE; dst = wo_t;
        srcN = EE; dstK = E2;
        n0 = (r >> 2) * 64; k0 = (r & 3) * 384;
    } else if (bid < 288) {           // W1: 48 n-panels x 2 k-panels
        const int r = bid - 192;
        src = W1 + (size_t)dl * EE * MLPD; dst = w1_t;
        srcN = MLPD; dstK = EE;
        n0 = (r >> 1) * 64; k0 = (r & 1) * 384;
    } else {                          // W2: 12 n-panels x 8 k-panels
        const int r = bid - 288;
        src = W2 + (size_t)dl * MLPD * EE; dst = w2_t;
        srcN = EE; dstK = MLPD;
        n0 = (r >> 3) * 64; k0 = (r & 7) * 384;
    }
    const int t = threadIdx.x;
    const int c = t & 63, kq = t >> 6;        // gather: col c, k-quarter kq

    for (int sub = 0; sub < 3; ++sub) {
        {
            const int row16 = t >> 4, nc = (t & 15) * 4;
            char* ldsb = (char*)tin;
#pragma unroll
            for (int i = 0; i < 8; ++i) {
                const int kr = i * 16 + row16;
                gld16(src + (size_t)(k0 + sub * 128 + kr) * srcN + n0 + nc,
                      ldsb + kr * 256 + (t & 15) * 16);
            }
        }
        asm volatile("s_waitcnt vmcnt(0)" ::: "memory");
        __syncthreads();
        bf16 a[32];
#pragma unroll
        for (int j = 0; j < 32; ++j)
            a[j] = __float2bfloat16(tin[(kq * 32 + j) * 64 + c]);
#pragma unroll
        for (int m = 0; m < 4; ++m) {
            const int kchunk = sub * 16 + kq * 4 + m;               // 0..47
            const int phys = (kchunk & ~7) | ((kchunk ^ c) & 7);
            *(uint4*)((char*)tout + c * 768 + phys * 16) = *(uint4*)&a[m * 8];
        }
        __syncthreads();
    }

#pragma unroll
    for (int it = 0; it < 12; ++it) {
        const int idx = it * 256 + t;
        const int r = idx / 48, ch = idx - r * 48;
        const int phys = (ch & ~7) | ((ch ^ r) & 7);
        *(uint4*)(dst + (size_t)(n0 + r) * dstK + k0 + ch * 8) =
            *(uint4*)((char*)tout + r * 768 + phys * 16);
    }
}

// ================= final LN (CLS rows, f32) =================
__global__ __launch_bounds__(256) void ln_cls(
    const float* __restrict__ h, const float* __restrict__ g,
    const float* __restrict__ bb, float* __restrict__ xr)
{
    const int b_ = blockIdx.x;
    const int t = threadIdx.x;
    const float* x = h + (size_t)(b_*NT)*EE;
    const float v0 = x[t], v1 = x[t+256], v2 = x[t+512];
    __shared__ float rs[256], rss[256];
    rs[t]  = v0+v1+v2;
    rss[t] = v0*v0+v1*v1+v2*v2;
    __syncthreads();
    for (int st = 128; st > 0; st >>= 1) {
        if (t < st) { rs[t] += rs[t+st]; rss[t] += rss[t+st]; }
        __syncthreads();
    }
    const float mean = rs[0] * (1.f/768.f);
    const float var  = rss[0] * (1.f/768.f) - mean*mean;
    const float rstd = rsqrtf(var + EPSF);
    float* o = xr + (size_t)b_ * EE;
    o[t]     = (v0-mean)*rstd*g[t]     + bb[t];
    o[t+256] = (v1-mean)*rstd*g[t+256] + bb[t+256];
    o[t+512] = (v2-mean)*rstd*g[t+512] + bb[t+512];
}

// ================= parallel classifier head =================
__global__ __launch_bounds__(256) void head_gemm(
    const float* __restrict__ xr, const float* __restrict__ hw,
    const float* __restrict__ hb, float* __restrict__ logits)
{
    const int b_ = blockIdx.y, ct = blockIdx.x;
    const int t = threadIdx.x;
    const int c_loc = t & 63, kp = t >> 6;
    const int c = ct * 64 + c_loc;
    __shared__ float xs[768];
    for (int i = t; i < 768; i += 256) xs[i] = xr[(size_t)b_*EE + i];
    __syncthreads();
    float acc = 0.f;
    if (c < NCLS) {
        const int k0 = kp * 192;
        for (int kk = k0; kk < k0 + 192; ++kk)
            acc += xs[kk] * hw[(size_t)kk * NCLS + c];
    }
    __shared__ float red[4][64];
    red[kp][c_loc] = acc;
    __syncthreads();
    if (kp == 0 && c < NCLS)
        logits[(size_t)b_*NCLS + c] =
            red[0][c_loc] + red[1][c_loc] + red[2][c_loc] + red[3][c_loc] + hb[c];
}

extern "C" void kernel_launch(void* const* d_in, const int* in_sizes, int n_in,
                              void* d_out, int out_size, void* d_ws, size_t ws_size,
                              hipStream_t stream)
{
    const float* x      = (const float*)d_in[0];
    const float* conv_w = (const float*)d_in[1];
    const float* conv_b = (const float*)d_in[2];
    const float* cls    = (const float*)d_in[3];
    const float* pos    = (const float*)d_in[4];
    const float* Wq     = (const float*)d_in[5];
    const float* Wk     = (const float*)d_in[6];
    const float* Wv     = (const float*)d_in[7];
    const float* lq1    = (const float*)d_in[8];
    const float* lk1    = (const float*)d_in[9];
    const float* lq2    = (const float*)d_in[10];
    const float* lk2    = (const float*)d_in[11];
    const float* gn_g   = (const float*)d_in[12];
    const float* gn_b   = (const float*)d_in[13];
    const float* Wo     = (const float*)d_in[14];
    const float* ln1_g  = (const float*)d_in[15];
    const float* ln1_b  = (const float*)d_in[16];
    const float* ln2_g  = (const float*)d_in[17];
    const float* ln2_b  = (const float*)d_in[18];
    const float* mlp_w1 = (const float*)d_in[19];
    const float* mlp_b1 = (const float*)d_in[20];
    const float* mlp_w2 = (const float*)d_in[21];
    const float* mlp_b2 = (const float*)d_in[22];
    const float* lnf_g  = (const float*)d_in[23];
    const float* lnf_b  = (const float*)d_in[24];
    const float* head_w = (const float*)d_in[25];
    const float* head_b = (const float*)d_in[26];

    float* out_f    = (float*)d_out;
    float* logits   = out_f;
    float* attn_out = out_f + (size_t)BB*NCLS;

    const int TOK = TOKC;
    const size_t TOKE = (size_t)TOK*EE;

    float* ws   = (float*)d_ws;
    float* h    = ws;
    float* o    = h + TOKE;
    float* Pp   = o + (size_t)BB*HH*NT*128;
    bf16*  Qrm  = (bf16*)(Pp + 2*TOKE);
    bf16*  Krm  = Qrm + (size_t)192*208*128;
    bf16*  Vf   = Krm + (size_t)192*208*128;
    bf16*  act2 = Vf + (size_t)192*7*8*512;
    bf16*  xn   = act2 + (size_t)TOK*MLPD;
    bf16*  wall = xn + TOKE;
    bf16*  cwbf = wall + (size_t)6*9437184;
    float* lam  = (float*)(cwbf + (size_t)EE*EE);
    float* xr   = lam + 128;
    float* gnst = xr + (size_t)BB*EE;

    hipMemsetAsync(Vf, 0, (size_t)192*7*8*512*2, stream);

    setup_misc<<<2353, 256, 0, stream>>>(conv_w, cwbf, cls, pos, h,
                                         lq1, lk1, lq2, lk2, lam);
    transpose_pack<<<6*384, 256, 0, stream>>>(Wq, Wk, Wv, Wo, mlp_w1, mlp_w2, wall);
    im2col_kernel<<<(3136*EE+255)/256, 256, 0, stream>>>(x, xn);
    gemm_bf16<<<dim3(EE/128, 25), 256, 0, stream>>>(
        xn, cwbf, conv_b, h, nullptr, nullptr, pos, 3136, EE, EE, EE, EE, 4);

    ln_rows<<<TOK, 256, 0, stream>>>(h, ln1_g, ln1_b, xn);

    for (int dl = 0; dl < ND; ++dl) {
        bf16* wq_t = wall + (size_t)dl*9437184;
        bf16* wo_t = wq_t + 3538944;
        bf16* w1_t = wo_t + 1179648;
        bf16* w2_t = w1_t + 2359296;

        gemm256t<4><<<dim3(4608/256, (TOK+255)/256), 512, 0, stream>>>(
            xn, wq_t, nullptr, (float*)Qrm, (float*)Krm, (float*)Vf,
            TOK, EE, 4608, 1);
        attn_mfma<<<2496, 64, 0, stream>>>(
            Qrm, Krm, Vf, lam + dl*HH, attn_out + (size_t)dl*BB*HH*NT*NT, o, gnst);
        gn_apply<<<dim3(4, BB*HH), 256, 0, stream>>>(
            o, gnst, gn_g + dl*128, gn_b + dl*128, act2);
        gemm_bf16<<<dim3(EE/128, 25, 2), 256, 0, stream>>>(
            act2, wo_t, nullptr, Pp, nullptr, nullptr, nullptr,
            TOK, E2/2, E2, E2, EE, 0);
        ln_fuse<<<TOK, 192, 0, stream>>>(
            h, Pp, nullptr, ln2_g + dl*EE, ln2_b + dl*EE, h, xn);
        gemm256t<3><<<dim3(MLPD/192, (TOK+255)/256), 512, 0, stream>>>(
            xn, w1_t, mlp_b1 + dl*MLPD, (float*)act2, nullptr, nullptr,
            TOK, EE, MLPD, 3);
        gemm_bf16<<<dim3(EE/128, 25, 2), 256, 0, stream>>>(
            act2, w2_t, nullptr, Pp, nullptr, nullptr, nullptr,
            TOK, MLPD/2, MLPD, MLPD, EE, 0);
        if (dl < ND-1)
            ln_fuse<<<TOK, 192, 0, stream>>>(
                h, Pp, mlp_b2 + dl*EE, ln1_g + (dl+1)*EE, ln1_b + (dl+1)*EE, h, xn);
        else
            ln_fuse<<<TOK, 192, 0, stream>>>(
                h, Pp, mlp_b2 + dl*EE, lnf_g, lnf_b, h, xn);
    }

    ln_cls<<<BB, 256, 0, stream>>>(h, lnf_g, lnf_b, xr);
    head_gemm<<<dim3(16, BB), 256, 0, stream>>>(xr, head_w, head_b, logits);
}